// Round 7
// baseline (652.127 us; speedup 1.0000x reference)
//
#include <hip/hip_runtime.h>
#include <stdint.h>
#include <stddef.h>

// Problem constants
#define T_ 512
#define B_ 256
#define IN_ 292
#define H_ 128
#define G4_ 512     // 4*H
#define TB_ 131072  // T_*B_
#define LCH 32      // time-chunk length (segment scan)
#define NCH 16      // chunks
#define KP_ 320     // K padded to 10*32

typedef short bf16x8 __attribute__((ext_vector_type(8)));
typedef float f32x4 __attribute__((ext_vector_type(4)));
typedef unsigned int u32t;

__device__ __forceinline__ unsigned short f2bf(float f) {
  unsigned u = __float_as_uint(f);
  u += 0x7FFFu + ((u >> 16) & 1u);   // RTNE
  return (unsigned short)(u >> 16);
}
__device__ __forceinline__ unsigned bfpack2(float a, float b) {
  unsigned ua = __float_as_uint(a) + 0x8000u;
  unsigned ub = __float_as_uint(b) + 0x8000u;
  return __builtin_amdgcn_perm(ub, ua, 0x07060302u);  // [b.hi16 : a.hi16]
}
__device__ __forceinline__ float sigf(float x) {
  return __builtin_amdgcn_rcpf(1.0f + __expf(-x));
}
__device__ __forceinline__ float tanhf_(float x) {
  return 1.0f - 2.0f * __builtin_amdgcn_rcpf(__expf(2.0f * x) + 1.0f);
}
__device__ __forceinline__ void barrier_lds() {
  asm volatile("s_waitcnt lgkmcnt(0)\n\ts_barrier" ::: "memory");
}
__device__ __forceinline__ void barrier_vm() {
  asm volatile("s_waitcnt vmcnt(0) lgkmcnt(0)\n\ts_barrier" ::: "memory");
}
// async global->LDS 16B/lane; LDS dst wave-uniform base (+lane*16 by HW)
__device__ __forceinline__ void gload_lds16(const void* g, void* l) {
  __builtin_amdgcn_global_load_lds(
      (const __attribute__((address_space(1))) u32t*)g,
      (__attribute__((address_space(3))) u32t*)l, 16, 0, 0);
}

// ---------------------------------------------------------------------------
// K0w: reorder+convert weights to jj = cell*4+gate layout.
//   Wb   bf16 [512][320]: row jj = Wih row (jj&3)*128 + (jj>>2), k-pad zeros
//   whh2 bf16 [512][128]: row jj = Whh row (jj&3)*128 + (jj>>2)
//   bias2 fp32 [512]: bih+bhh reordered
// ---------------------------------------------------------------------------
__global__ __launch_bounds__(256) void k0w_cvt(
    const float* __restrict__ Wih, const float* __restrict__ Whh,
    const float* __restrict__ bih, const float* __restrict__ bhh,
    unsigned short* __restrict__ Wb, unsigned short* __restrict__ whh2,
    float* __restrict__ bias2) {
  const int g = blockIdx.x * 256 + threadIdx.x;
  if (g < 512) {
    const int sb = (g & 3) * 128 + (g >> 2);
    bias2[g] = bih[sb] + bhh[sb];
  }
  if (g < 20480) {
    const int jj = g / 40, s = g % 40;
    const int src = (jj & 3) * 128 + (jj >> 2);
    float4 a = {0.f,0.f,0.f,0.f}, b = {0.f,0.f,0.f,0.f};
    const float* p = Wih + (size_t)src * IN_ + 8 * s;
    if (s < 36) { a = *(const float4*)p; b = *(const float4*)(p + 4); }
    else if (s == 36) { a = *(const float4*)p; }  // floats 288..291
    uint4 o;
    o.x = bfpack2(a.x,a.y); o.y = bfpack2(a.z,a.w);
    o.z = bfpack2(b.x,b.y); o.w = bfpack2(b.z,b.w);
    *(uint4*)&Wb[(size_t)jj * KP_ + 8 * s] = o;
  } else if (g < 28672) {
    const int g2 = g - 20480;
    const int jj = g2 >> 4, s = g2 & 15;
    const int src = (jj & 3) * 128 + (jj >> 2);
    const float* p = Whh + (size_t)src * H_ + 8 * s;
    float4 a = *(const float4*)p, b = *(const float4*)(p + 4);
    uint4 o;
    o.x = bfpack2(a.x,a.y); o.y = bfpack2(a.z,a.w);
    o.z = bfpack2(b.x,b.y); o.w = bfpack2(b.z,b.w);
    *(uint4*)&whh2[(size_t)jj * H_ + 8 * s] = o;
  }
}

// ---------------------------------------------------------------------------
// Fused-scan building blocks.
// x window = 64 rows (r = 16*t' + b, t' 0..3) x 292 k. LDS xs: [64 rows] x
// [72 granules of 16B] (k 0..287), XOR-swizzled within each 8-granule k-tile
// (slot = g ^ (row&7)) to kill 16-way bank conflicts; xtl: granule 72
// (k 288..291) per row.
// ---------------------------------------------------------------------------
__device__ __forceinline__ void dma_window(
    const float* __restrict__ x, float* xs, float* xtl,
    int tbase /* t0+4u */, int bg, int w, int lane) {
#pragma unroll
  for (int j = 0; j < 9; j++) {
    const int g = w * 576 + 64 * j + lane;
    const int row = g / 72;
    const int sl = g % 72;
    const int srcg = (sl & ~7) + ((sl & 7) ^ (row & 7));
    const int grow = (tbase + (row >> 4)) * B_ + bg * 16 + (row & 15);
    gload_lds16(x + (size_t)grow * IN_ + srcg * 4, xs + (w * 576 + 64 * j) * 4);
  }
  if (w == 0) {
    const int grow = (tbase + (lane >> 4)) * B_ + bg * 16 + (lane & 15);
    gload_lds16(x + (size_t)grow * IN_ + 288, xtl);
  }
}

// GEMM over one window: acc[s][ms] (ms = t') for wave w's jj [64w..64w+64).
// A = Wb rows (direct L2->reg, dist-2 prefetch), B = x from swizzled LDS.
__device__ __forceinline__ void window_gemm(
    const float* xs, const float* xtl, const unsigned short* __restrict__ Wb,
    int w, int q, int l15, f32x4 acc[4][4]) {
#pragma unroll
  for (int s = 0; s < 4; s++)
#pragma unroll
    for (int ms = 0; ms < 4; ms++) acc[s][ms] = (f32x4){0.f,0.f,0.f,0.f};

  const unsigned short* wrow[4];
  bf16x8 af_c[4], af_n[4];
#pragma unroll
  for (int s = 0; s < 4; s++) {
    wrow[s] = Wb + (size_t)(w * 64 + 16 * s + l15) * KP_ + q * 8;
    af_c[s] = *(const bf16x8*)wrow[s];
    af_n[s] = *(const bf16x8*)(wrow[s] + 32);
  }
#pragma unroll
  for (int it = 0; it < 9; it++) {
    bf16x8 bfr[4];
#pragma unroll
    for (int ms = 0; ms < 4; ms++) {
      const int row = 16 * ms + l15;
      const int m8 = row & 7;
      const float* rp = xs + row * 288 + it * 32;
      float4 a = *(const float4*)(rp + (((2 * q)     ^ m8) * 4));
      float4 b = *(const float4*)(rp + (((2 * q + 1) ^ m8) * 4));
      uint4 v;
      v.x = bfpack2(a.x,a.y); v.y = bfpack2(a.z,a.w);
      v.z = bfpack2(b.x,b.y); v.w = bfpack2(b.z,b.w);
      bfr[ms] = *(bf16x8*)&v;
    }
#pragma unroll
    for (int s = 0; s < 4; s++)
#pragma unroll
      for (int ms = 0; ms < 4; ms++)
        acc[s][ms] = __builtin_amdgcn_mfma_f32_16x16x32_bf16(
            af_c[s], bfr[ms], acc[s][ms], 0, 0, 0);
#pragma unroll
    for (int s = 0; s < 4; s++) af_c[s] = af_n[s];
    if (it < 8) {
#pragma unroll
      for (int s = 0; s < 4; s++)
        af_n[s] = *(const bf16x8*)(wrow[s] + 32 * (it + 2));
    }
  }
  // tail k-tile 9: k 288..291 real (q==0 lanes), rest zero; W pad is zero.
  {
    bf16x8 bfr[4];
#pragma unroll
    for (int ms = 0; ms < 4; ms++) {
      uint4 v = {0u,0u,0u,0u};
      if (q == 0) {
        const float4 t = *(const float4*)(xtl + (16 * ms + l15) * 4);
        v.x = bfpack2(t.x,t.y); v.y = bfpack2(t.z,t.w);
      }
      bfr[ms] = *(bf16x8*)&v;
    }
#pragma unroll
    for (int s = 0; s < 4; s++)
#pragma unroll
      for (int ms = 0; ms < 4; ms++)
        acc[s][ms] = __builtin_amdgcn_mfma_f32_16x16x32_bf16(
            af_c[s], bfr[ms], acc[s][ms], 0, 0, 0);
  }
}

// ---------------------------------------------------------------------------
// k2a_f: per (bg,ck) block: fused x-GEMM + from-zero scan. 256 blocks, 512thr.
// Lane (w,q,l15) owns cells {16w+4s+q | s=0..3}, batch l15. Outputs stored
// from first reset onward (vld), h dumped coalesced one step deferred.
// ---------------------------------------------------------------------------
__global__ __launch_bounds__(512, 2) void k2a_f(
    const float* __restrict__ x, const unsigned short* __restrict__ Wb,
    const float* __restrict__ bias2, const unsigned short* __restrict__ whh2,
    const int* __restrict__ done, unsigned short* __restrict__ hidden,
    unsigned short* __restrict__ hfin, float* __restrict__ cfin) {
  __shared__ float xs[64 * 288];        // 72 KB
  __shared__ float xtl[64 * 4];         // 1 KB
  __shared__ unsigned short hs[2][16 * 136];
  __shared__ int dns[LCH * 16];

  const int bg = blockIdx.x & 15;
  const int ck = blockIdx.x >> 4;
  const int t0 = ck * LCH;
  const int tid = threadIdx.x;
  const int w = tid >> 6;
  const int lane = tid & 63;
  const int l15 = lane & 15;
  const int q = lane >> 4;
  const int bglob = bg * 16 + l15;
  const int b_d = tid >> 5;             // dump-thread batch
  const int kd = (tid & 31) * 4;        // dump-thread cell base

  dma_window(x, xs, xtl, t0, bg, w, lane);  // window 0 in flight

  dns[tid] = done[(size_t)(t0 + (tid >> 4)) * B_ + bg * 16 + (tid & 15)];

  bf16x8 wf[4][4];
#pragma unroll
  for (int s = 0; s < 4; s++)
#pragma unroll
    for (int kc = 0; kc < 4; kc++)
      wf[s][kc] = *(const bf16x8*)&whh2[(size_t)(w * 64 + 16 * s + l15) * H_ + kc * 32 + q * 8];
  float4 bias_r[4];
#pragma unroll
  for (int s = 0; s < 4; s++)
    bias_r[s] = *(const float4*)&bias2[w * 64 + 16 * s + 4 * q];

  float c_[4] = {0.f, 0.f, 0.f, 0.f};
  *(ushort4*)&hs[0][b_d * 136 + kd] = (ushort4){0, 0, 0, 0};
  bool vldL = false;
  unsigned short hl[4] = {0, 0, 0, 0};
  int cur = 0;
  barrier_lds();

  f32x4 accx[4][4];
#pragma unroll 1
  for (int tloc = 0; tloc < LCH; tloc++) {
    // deferred coalesced dump of h(t-1)
    if (tloc > 0 && vldL) {
      uint2 hv = *(const uint2*)&hs[cur][b_d * 136 + kd];
      *(uint2*)&hidden[((size_t)(t0 + tloc - 1) * B_ + bg * 16 + b_d) * H_ + kd] = hv;
    }
    vldL = vldL || (dns[tloc * 16 + b_d] != 0);

    if ((tloc & 3) == 0) {
      barrier_vm();                      // DMA(u) landed everywhere
      window_gemm(xs, xtl, Wb, w, q, l15, accx);
      barrier_lds();                     // all waves done reading xs
      if (tloc < LCH - 4)
        dma_window(x, xs, xtl, t0 + tloc + 4, bg, w, lane);  // prefetch u+1
    }

    const int dn = dns[tloc * 16 + l15];
    bf16x8 hf[4];
#pragma unroll
    for (int kc = 0; kc < 4; kc++) {
      bf16x8 v = *(const bf16x8*)&hs[cur][l15 * 136 + kc * 32 + q * 8];
      if (dn) v = (bf16x8){0,0,0,0,0,0,0,0};
      hf[kc] = v;
    }
    f32x4 acch[4];
#pragma unroll
    for (int s = 0; s < 4; s++) acch[s] = (f32x4){0.f,0.f,0.f,0.f};
#pragma unroll
    for (int s = 0; s < 4; s++)
#pragma unroll
      for (int kc = 0; kc < 4; kc++)
        acch[s] = __builtin_amdgcn_mfma_f32_16x16x32_bf16(
            wf[s][kc], hf[kc], acch[s], 0, 0, 0);

    const float mm = dn ? 0.0f : 1.0f;
    const int d = tloc & 3;
#pragma unroll
    for (int s = 0; s < 4; s++) {
      const float iv = accx[s][d][0] + acch[s][0] + bias_r[s].x;
      const float fv = accx[s][d][1] + acch[s][1] + bias_r[s].y;
      const float gv = accx[s][d][2] + acch[s][2] + bias_r[s].z;
      const float ov = accx[s][d][3] + acch[s][3] + bias_r[s].w;
      float cc = c_[s] * mm;
      cc = sigf(fv) * cc + sigf(iv) * tanhf_(gv);
      c_[s] = cc;
      const unsigned short hu = f2bf(sigf(ov) * tanhf_(cc));
      hs[cur ^ 1][l15 * 136 + 16 * w + 4 * s + q] = hu;
      hl[s] = hu;
    }
    barrier_lds();
    cur ^= 1;
  }
  if (vldL) {
    uint2 hv = *(const uint2*)&hs[cur][b_d * 136 + kd];
    *(uint2*)&hidden[((size_t)(t0 + LCH - 1) * B_ + bg * 16 + b_d) * H_ + kd] = hv;
  }
#pragma unroll
  for (int s = 0; s < 4; s++) {
    const int cell = 16 * w + 4 * s + q;
    hfin[((size_t)ck * B_ + bglob) * H_ + cell] = hl[s];
    cfin[((size_t)ck * B_ + bglob) * H_ + cell] = c_[s];
  }
  asm volatile("s_waitcnt vmcnt(0)" ::: "memory");
}

// ---------------------------------------------------------------------------
// k2b_f: per (bg,ck) prefix recompute from TRUE carry (k2a finals of ck-1).
// Synchronous per-window DMA+GEMM; stores while act; flags needfix.
// ---------------------------------------------------------------------------
__global__ __launch_bounds__(512, 2) void k2b_f(
    const float* __restrict__ x, const unsigned short* __restrict__ Wb,
    const float* __restrict__ bias2, const unsigned short* __restrict__ whh2,
    const float* __restrict__ h0, const float* __restrict__ c0,
    const int* __restrict__ done, unsigned short* __restrict__ hidden,
    const unsigned short* __restrict__ hfin, const float* __restrict__ cfin,
    int* __restrict__ needfix) {
  __shared__ float xs[64 * 288];
  __shared__ float xtl[64 * 4];
  __shared__ unsigned short hs[2][16 * 136];
  __shared__ int dns[LCH * 16];

  const int bg = blockIdx.x & 15;
  const int ck = blockIdx.x >> 4;
  const int t0 = ck * LCH;
  const int tid = threadIdx.x;
  const int w = tid >> 6;
  const int lane = tid & 63;
  const int l15 = lane & 15;
  const int q = lane >> 4;
  const int bglob = bg * 16 + l15;
  const int b_d = tid >> 5;
  const int kd = (tid & 31) * 4;

  dns[tid] = done[(size_t)(t0 + (tid >> 4)) * B_ + bg * 16 + (tid & 15)];

  bf16x8 wf[4][4];
#pragma unroll
  for (int s = 0; s < 4; s++)
#pragma unroll
    for (int kc = 0; kc < 4; kc++)
      wf[s][kc] = *(const bf16x8*)&whh2[(size_t)(w * 64 + 16 * s + l15) * H_ + kc * 32 + q * 8];
  float4 bias_r[4];
#pragma unroll
  for (int s = 0; s < 4; s++)
    bias_r[s] = *(const float4*)&bias2[w * 64 + 16 * s + 4 * q];

  float c_[4];
  if (ck == 0) {
    float4 hv4 = *(const float4*)(h0 + (size_t)(bg * 16 + b_d) * H_ + kd);
    uint2 hp = {bfpack2(hv4.x, hv4.y), bfpack2(hv4.z, hv4.w)};
    *(uint2*)&hs[0][b_d * 136 + kd] = hp;
#pragma unroll
    for (int s = 0; s < 4; s++)
      c_[s] = c0[(size_t)bglob * H_ + 16 * w + 4 * s + q];
  } else {
    ushort4 hv = *(const ushort4*)&hfin[((size_t)(ck - 1) * B_ + bg * 16 + b_d) * H_ + kd];
    *(ushort4*)&hs[0][b_d * 136 + kd] = hv;
#pragma unroll
    for (int s = 0; s < 4; s++)
      c_[s] = cfin[((size_t)(ck - 1) * B_ + bglob) * H_ + 16 * w + 4 * s + q];
  }
  bool actL = true;   // dump-thread predicate (batch b_d)
  bool act = true;    // scan-lane predicate (batch l15)
  bool broke = false;
  int cur = 0;
  barrier_lds();

  f32x4 accx[4][4];
#pragma unroll 1
  for (int tloc = 0; tloc < LCH; tloc++) {
    if (tloc > 0 && actL) {
      uint2 hv = *(const uint2*)&hs[cur][b_d * 136 + kd];
      *(uint2*)&hidden[((size_t)(t0 + tloc - 1) * B_ + bg * 16 + b_d) * H_ + kd] = hv;
    }
    actL = actL && (dns[tloc * 16 + b_d] == 0);

    const int dn = dns[tloc * 16 + l15];
    const bool nact = act && (dn == 0);
    if (__ballot(nact) == 0ULL) { act = false; broke = true; break; }
    act = nact;

    if ((tloc & 3) == 0) {
      dma_window(x, xs, xtl, t0 + tloc, bg, w, lane);
      barrier_vm();
      window_gemm(xs, xtl, Wb, w, q, l15, accx);
    }

    bf16x8 hf[4];
#pragma unroll
    for (int kc = 0; kc < 4; kc++)
      hf[kc] = *(const bf16x8*)&hs[cur][l15 * 136 + kc * 32 + q * 8];
    f32x4 acch[4];
#pragma unroll
    for (int s = 0; s < 4; s++) acch[s] = (f32x4){0.f,0.f,0.f,0.f};
#pragma unroll
    for (int s = 0; s < 4; s++)
#pragma unroll
      for (int kc = 0; kc < 4; kc++)
        acch[s] = __builtin_amdgcn_mfma_f32_16x16x32_bf16(
            wf[s][kc], hf[kc], acch[s], 0, 0, 0);

    const int d = tloc & 3;
#pragma unroll
    for (int s = 0; s < 4; s++) {
      const float iv = accx[s][d][0] + acch[s][0] + bias_r[s].x;
      const float fv = accx[s][d][1] + acch[s][1] + bias_r[s].y;
      const float gv = accx[s][d][2] + acch[s][2] + bias_r[s].z;
      const float ov = accx[s][d][3] + acch[s][3] + bias_r[s].w;
      float cc = sigf(fv) * c_[s] + sigf(iv) * tanhf_(gv);
      c_[s] = cc;
      hs[cur ^ 1][l15 * 136 + 16 * w + 4 * s + q] = f2bf(sigf(ov) * tanhf_(cc));
    }
    barrier_lds();
    cur ^= 1;
  }
  if (!broke && actL) {
    uint2 hv = *(const uint2*)&hs[cur][b_d * 136 + kd];
    *(uint2*)&hidden[((size_t)(t0 + LCH - 1) * B_ + bg * 16 + b_d) * H_ + kd] = hv;
  }
  if (tid == 0) needfix[blockIdx.x] = (__ballot(act) != 0ULL) ? 1 : 0;
  asm volatile("s_waitcnt vmcnt(0)" ::: "memory");
}

// ---------------------------------------------------------------------------
// k2c_f: sequential exact guard (expected no-op). 16 blocks.
// ---------------------------------------------------------------------------
__global__ __launch_bounds__(512, 2) void k2c_f(
    const float* __restrict__ x, const unsigned short* __restrict__ Wb,
    const float* __restrict__ bias2, const unsigned short* __restrict__ whh2,
    const float* __restrict__ h0, const float* __restrict__ c0,
    const int* __restrict__ done, unsigned short* __restrict__ hidden,
    const unsigned short* __restrict__ hfin, const float* __restrict__ cfin,
    const int* __restrict__ needfix) {
  const int bg = blockIdx.x;
  bool dirty = false;
  for (int c2 = 0; c2 < NCH - 1; c2++) dirty |= (needfix[c2 * 16 + bg] != 0);
  if (!dirty) return;

  __shared__ float xs[64 * 288];
  __shared__ float xtl[64 * 4];
  __shared__ unsigned short hs[2][16 * 136];
  __shared__ int dns[T_ * 16];  // 32 KB

  const int tid = threadIdx.x;
  const int w = tid >> 6;
  const int lane = tid & 63;
  const int l15 = lane & 15;
  const int q = lane >> 4;
  const int bglob = bg * 16 + l15;
  const int b_d = tid >> 5;
  const int kd = (tid & 31) * 4;

  {
    const int* p = done + (size_t)tid * B_ + bg * 16;
    *(int4*)&dns[tid * 16]      = *(const int4*)(p);
    *(int4*)&dns[tid * 16 + 4]  = *(const int4*)(p + 4);
    *(int4*)&dns[tid * 16 + 8]  = *(const int4*)(p + 8);
    *(int4*)&dns[tid * 16 + 12] = *(const int4*)(p + 12);
  }

  bf16x8 wf[4][4];
#pragma unroll
  for (int s = 0; s < 4; s++)
#pragma unroll
    for (int kc = 0; kc < 4; kc++)
      wf[s][kc] = *(const bf16x8*)&whh2[(size_t)(w * 64 + 16 * s + l15) * H_ + kc * 32 + q * 8];
  float4 bias_r[4];
#pragma unroll
  for (int s = 0; s < 4; s++)
    bias_r[s] = *(const float4*)&bias2[w * 64 + 16 * s + 4 * q];

  float c_[4];
  {
    float4 hv4 = *(const float4*)(h0 + (size_t)(bg * 16 + b_d) * H_ + kd);
    uint2 hp = {bfpack2(hv4.x, hv4.y), bfpack2(hv4.z, hv4.w)};
    *(uint2*)&hs[0][b_d * 136 + kd] = hp;
#pragma unroll
    for (int s = 0; s < 4; s++)
      c_[s] = c0[(size_t)bglob * H_ + 16 * w + 4 * s + q];
  }
  int cur = 0;
  barrier_lds();

#pragma unroll 1
  for (int ck = 0; ck < NCH; ck++) {
    const int t0 = ck * LCH;
    bool act = true, actL = true, broke = false;
    f32x4 accx[4][4];
#pragma unroll 1
    for (int tloc = 0; tloc < LCH; tloc++) {
      if (tloc > 0 && actL) {
        uint2 hv = *(const uint2*)&hs[cur][b_d * 136 + kd];
        *(uint2*)&hidden[((size_t)(t0 + tloc - 1) * B_ + bg * 16 + b_d) * H_ + kd] = hv;
      }
      actL = actL && (dns[(t0 + tloc) * 16 + b_d] == 0);

      const int dn = dns[(t0 + tloc) * 16 + l15];
      const bool nact = act && (dn == 0);
      if (__ballot(nact) == 0ULL) { act = false; broke = true; break; }
      act = nact;

      if ((tloc & 3) == 0) {
        dma_window(x, xs, xtl, t0 + tloc, bg, w, lane);
        barrier_vm();
        window_gemm(xs, xtl, Wb, w, q, l15, accx);
      }

      bf16x8 hf[4];
#pragma unroll
      for (int kc = 0; kc < 4; kc++)
        hf[kc] = *(const bf16x8*)&hs[cur][l15 * 136 + kc * 32 + q * 8];
      f32x4 acch[4];
#pragma unroll
      for (int s = 0; s < 4; s++) acch[s] = (f32x4){0.f,0.f,0.f,0.f};
#pragma unroll
      for (int s = 0; s < 4; s++)
#pragma unroll
        for (int kc = 0; kc < 4; kc++)
          acch[s] = __builtin_amdgcn_mfma_f32_16x16x32_bf16(
              wf[s][kc], hf[kc], acch[s], 0, 0, 0);

      const int d = tloc & 3;
#pragma unroll
      for (int s = 0; s < 4; s++) {
        const float iv = accx[s][d][0] + acch[s][0] + bias_r[s].x;
        const float fv = accx[s][d][1] + acch[s][1] + bias_r[s].y;
        const float gv = accx[s][d][2] + acch[s][2] + bias_r[s].z;
        const float ov = accx[s][d][3] + acch[s][3] + bias_r[s].w;
        float cc = sigf(fv) * c_[s] + sigf(iv) * tanhf_(gv);
        c_[s] = cc;
        hs[cur ^ 1][l15 * 136 + 16 * w + 4 * s + q] = f2bf(sigf(ov) * tanhf_(cc));
      }
      barrier_lds();
      cur ^= 1;
    }
    if (!broke && actL) {
      uint2 hv = *(const uint2*)&hs[cur][b_d * 136 + kd];
      *(uint2*)&hidden[((size_t)(t0 + LCH - 1) * B_ + bg * 16 + b_d) * H_ + kd] = hv;
    }
    // chunk boundary: batches that reset adopt k2a's exact from-zero finals
    if (!act) {
#pragma unroll
      for (int s = 0; s < 4; s++) {
        const int cell = 16 * w + 4 * s + q;
        c_[s] = cfin[((size_t)ck * B_ + bglob) * H_ + cell];
        hs[cur][l15 * 136 + cell] = hfin[((size_t)ck * B_ + bglob) * H_ + cell];
      }
    }
    barrier_lds();
  }
  asm volatile("s_waitcnt vmcnt(0)" ::: "memory");
}

// ---------------------------------------------------------------------------
// K3: out[T*B][13] = hidden @ [W_pi; W_v]^T + [b_pi; b_v]   (unchanged)
// ---------------------------------------------------------------------------
__global__ __launch_bounds__(256) void k3_head(
    const unsigned short* __restrict__ hidden, const float* __restrict__ Wpi,
    const float* __restrict__ bpi, const float* __restrict__ Wv,
    const float* __restrict__ bv, float* __restrict__ out) {
  __shared__ unsigned short hs3[64 * 136];
  __shared__ float bias_s[16];

  const int tid = threadIdx.x;
  const int w = tid >> 6;
  const int lane = tid & 63;
  const int l15 = lane & 15;
  const int q = lane >> 4;
  const int m0 = blockIdx.x * 64;

  if (tid < 16) bias_s[tid] = (tid < 12) ? bpi[tid] : ((tid == 12) ? bv[0] : 0.f);

  bf16x8 wf3[4];
#pragma unroll
  for (int kc = 0; kc < 4; kc++) {
    float4 u0 = {0.f,0.f,0.f,0.f}, u1 = {0.f,0.f,0.f,0.f};
    if (l15 < 12) {
      const float* p = Wpi + (size_t)l15 * H_ + kc * 32 + q * 8;
      u0 = *(const float4*)p; u1 = *(const float4*)(p + 4);
    } else if (l15 == 12) {
      const float* p = Wv + kc * 32 + q * 8;
      u0 = *(const float4*)p; u1 = *(const float4*)(p + 4);
    }
    uint4 v;
    v.x = bfpack2(u0.x,u0.y); v.y = bfpack2(u0.z,u0.w);
    v.z = bfpack2(u1.x,u1.y); v.w = bfpack2(u1.z,u1.w);
    wf3[kc] = *(bf16x8*)&v;
  }

  {
    const int row = tid >> 2, ks = (tid & 3) * 32;
    const unsigned short* p = hidden + (size_t)(m0 + row) * H_ + ks;
#pragma unroll
    for (int i = 0; i < 4; i++)
      *(uint4*)&hs3[row * 136 + ks + i * 8] = *(const uint4*)(p + i * 8);
  }
  __syncthreads();

  f32x4 acc = (f32x4){0.f,0.f,0.f,0.f};
#pragma unroll
  for (int kc = 0; kc < 4; kc++) {
    bf16x8 hf = *(bf16x8*)&hs3[(16 * w + l15) * 136 + kc * 32 + q * 8];
    acc = __builtin_amdgcn_mfma_f32_16x16x32_bf16(wf3[kc], hf, acc, 0, 0, 0);
  }

  const float4 bb = *(float4*)&bias_s[4 * q];
  const int m = m0 + 16 * w + l15;
  const size_t ro = (size_t)m * 13;
  float v0 = acc[0] + bb.x, v1 = acc[1] + bb.y, v2 = acc[2] + bb.z, v3 = acc[3] + bb.w;
  if (q < 3) {
    out[ro + 4 * q + 0] = v0;
    out[ro + 4 * q + 1] = v1;
    out[ro + 4 * q + 2] = v2;
    out[ro + 4 * q + 3] = v3;
  } else {
    out[ro + 12] = v0;
  }
}

// ---------------------------------------------------------------------------
// ws: hidden bf16 [131072][128] @ 0 (33.5 MB). No pre2 anymore.
// d_out scratch (overwritten by K3 at the end):
//   Wb @0 (320KB), bias2 @512K, whh2 @640K (128KB),
//   hfin @1M (1MB), cfin @2M (2MB), needfix @4M (1KB)
// ---------------------------------------------------------------------------
extern "C" void kernel_launch(void* const* d_in, const int* in_sizes, int n_in,
                              void* d_out, int out_size, void* d_ws, size_t ws_size,
                              hipStream_t stream) {
  const float* x    = (const float*)d_in[0];
  const int* done   = (const int*)d_in[1];
  const float* h0   = (const float*)d_in[2];
  const float* c0   = (const float*)d_in[3];
  const float* Wih  = (const float*)d_in[4];
  const float* Whh  = (const float*)d_in[5];
  const float* bih  = (const float*)d_in[6];
  const float* bhh  = (const float*)d_in[7];
  const float* Wpi  = (const float*)d_in[8];
  const float* bpi  = (const float*)d_in[9];
  const float* Wv   = (const float*)d_in[10];
  const float* bv   = (const float*)d_in[11];
  (void)in_sizes; (void)n_in; (void)out_size; (void)ws_size;

  unsigned short* hidden = (unsigned short*)d_ws;
  unsigned short* Wb    = (unsigned short*)d_out;
  float* bias2          = (float*)((char*)d_out + (512u << 10));
  unsigned short* whh2  = (unsigned short*)((char*)d_out + (640u << 10));
  unsigned short* hfin  = (unsigned short*)((char*)d_out + (1u << 20));
  float* cfin           = (float*)((char*)d_out + (2u << 20));
  int* needfix          = (int*)((char*)d_out + (4u << 20));
  float* out = (float*)d_out;

  k0w_cvt<<<112, 256, 0, stream>>>(Wih, Whh, bih, bhh, Wb, whh2, bias2);
  k2a_f<<<256, 512, 0, stream>>>(x, Wb, bias2, whh2, done, hidden, hfin, cfin);
  k2b_f<<<256, 512, 0, stream>>>(x, Wb, bias2, whh2, h0, c0, done, hidden,
                                 hfin, cfin, needfix);
  k2c_f<<<16, 512, 0, stream>>>(x, Wb, bias2, whh2, h0, c0, done, hidden,
                                hfin, cfin, needfix);
  k3_head<<<TB_ / 64, 256, 0, stream>>>(hidden, Wpi, bpi, Wv, bv, out);
}